// Round 18
// baseline (448.202 us; speedup 1.0000x reference)
//
#include <hip/hip_runtime.h>
#include <cmath>

#define NS 51
#define ND 50
#define PLANE 1048576            // 1024*1024 (elements per plane)
#define DOG_ELEMS (ND * PLANE)   // 52428800
#define WPSTRIDE 160             // padded 1-D kernel: 17 zeros | taps | zeros

typedef __attribute__((ext_vector_type(8))) _Float16 half8;

// ---------------- K0: extract normalized 1-D kernels + radii --------------------
__global__ void dog_prep(const float* __restrict__ weight,
                         float* __restrict__ wp,
                         int* __restrict__ rarr, int S) {
    int i = blockIdx.x;
    int t = threadIdx.x;
    int R = (S - 1) >> 1;
    const float* row = weight + ((size_t)i * S + R) * S;   // center row of scale i
    __shared__ float sr[128];
    __shared__ float ssum;
    __shared__ int spad;
    if (t < S) sr[t] = row[t];
    for (int j = t; j < WPSTRIDE; j += blockDim.x) wp[i * WPSTRIDE + j] = 0.f;
    __syncthreads();
    if (t == 0) {
        float sum = 0.f;
        for (int j = 0; j < S; ++j) sum += sr[j];
        int pad = 0;
        while (pad < R && sr[pad] == 0.f) ++pad;
        ssum = sum; spad = pad;
        rarr[i] = R - pad;
    }
    __syncthreads();
    int pad = spad;
    int r = R - pad;
    float inv = 1.f / ssum;
    for (int j = t; j <= 2 * r; j += blockDim.x)
        wp[i * WPSTRIDE + 17 + j] = sr[pad + j] * inv;
}

// ---------------- K1: horizontal blur (R14 structure; fp16 output) --------------
__global__ __launch_bounds__(256) void dog_hblur(
        const float* __restrict__ in, _Float16* __restrict__ tmpHh,
        const float* __restrict__ wp, const int* __restrict__ rarr) {
    const int lo_t[5] = {0, 17, 28, 37, 44};
    const int hi_t[5] = {17, 28, 37, 44, 51};
    int t = threadIdx.x;
    int grp = t >> 7;
    int tl = t & 127;
    int y = (blockIdx.x << 1) | grp;
    int zc = blockIdx.y;
    __shared__ float srow[2][1284];                 // 321 swizzled float4 slots
    const float* inrow = in + ((size_t)y << 10);
    for (int f = tl; f < 286; f += 128) {           // elements 4f-56 .. 4f-53
        int xg = (f << 2) - 56;
        float4 v = make_float4(0.f, 0.f, 0.f, 0.f);
        if (xg >= 0 && xg <= 1020) {
            v = *(const float4*)(inrow + xg);
        } else {
            float vv[4];
#pragma unroll
            for (int c = 0; c < 4; ++c) {
                int g = xg + c;
                vv[c] = ((unsigned)g < 1024u) ? inrow[g] : 0.f;
            }
            v = make_float4(vv[0], vv[1], vv[2], vv[3]);
        }
        int fs = f + (f >> 3);                      // swizzled float4 index
        *(float4*)&srow[grp][fs << 2] = v;
    }
    __syncthreads();
    const float* s = srow[grp];
    for (int i = lo_t[zc]; i < hi_t[zc]; ++i) {
        int r = rarr[i];
        int c0 = 56 - r;
        int d = c0 & 7;
        int c0a = c0 - d;
        const float* __restrict__ w2 = wp + i * WPSTRIDE + 17 - d;
        int mcount = ((2 * r + d + 15) >> 3) << 3;  // >= 2r+d+8, mult of 8
        float acc[8];
#pragma unroll
        for (int k = 0; k < 8; ++k) acc[k] = 0.f;
        int ft = (c0a >> 2) + (tl << 1);            // base float4 index
        for (int m = 0; m < mcount; m += 8) {
            int f  = ft + (m >> 2);
            int fa = f + (f >> 3);
            int fb = (f + 1) + ((f + 1) >> 3);
            float4 va = *(const float4*)&s[fa << 2];
            float4 vb = *(const float4*)&s[fb << 2];
            float v[8] = {va.x, va.y, va.z, va.w, vb.x, vb.y, vb.z, vb.w};
#pragma unroll
            for (int j2 = 0; j2 < 8; ++j2)
#pragma unroll
                for (int k = 0; k < 8; ++k)
                    acc[k] = fmaf(w2[m + j2 - k], v[j2], acc[k]);
        }
        _Float16* o = tmpHh + (((size_t)i) << 20) + ((size_t)y << 10) + (tl << 3);
        half8 h;
#pragma unroll
        for (int k = 0; k < 8; ++k) h[k] = (_Float16)acc[k];
        *(half8*)o = h;                             // 16B store
    }
}

// ---------------- K2: fused vconv + DoG + 3x3x3 pool + epilogue -----------------
// R14 schedule exactly; ONE change: tmpH/LDS stage in fp16. LDS 27.5 KB ->
// 4 blocks/CU (32 waves/CU, was 24); staging chunks 16B = 8 halves, 10/row
// (80-half row, 160B stride -> conv reads 2-way bank-free); conv converts
// per element (ds_read_u16 + v_cvt_f32_f16). Numerics: R9 measured absmax
// unchanged (0.0039) with fp16 tmpH.

#define FMAG(W, V, MM) do {                                                       \
_Pragma("unroll")                                                                 \
    for (int j_ = 0; j_ < 8; ++j_)                                                \
_Pragma("unroll")                                                                 \
        for (int k_ = 0; k_ < 10; ++k_)                                           \
            acc[k_] = fmaf((W)[17 + (MM) + j_ - k_], V[j_], acc[k_]);             \
    } while (0)

__global__ __launch_bounds__(512, 8) void dog_fused(
        const _Float16* __restrict__ tmpHh, float* __restrict__ out,
        const float* __restrict__ wp, const int* __restrict__ rarr,
        const float* __restrict__ sigmas, const float* __restrict__ thr_p) {
    const int jlo_t[5] = {0, 17, 28, 37, 44};
    const int jhi_t[5] = {16, 27, 36, 43, 49};
    int p = blockIdx.x;                   // 0..1407
    int xcd = p & 7;
    int q = p >> 3;                       // 0..175
    int c8 = q >> 4;                      // 0..10
    int ybg = q & 15;                     // 0..15  (same-XCD consecutive y-blocks)
    int combo = (c8 << 3) | xcd;          // 0..87
    if (combo >= 85) return;              // pad blocks
    int wx = combo % 17;                  // 0..16
    int zc = combo / 17;                  // 0..4
    int t = threadIdx.x;
    int lane = t & 63;
    int wv = t >> 6;                      // 0..7
    int y0u = __builtin_amdgcn_readfirstlane((ybg << 6) + (wv << 3));
    int x0 = wx * 62 - 1;
    int x = x0 + lane;                    // -1 .. 1054
    int xa = x0 & ~7;                     // 16B-aligned stage base col (halves)
    int lx = (x0 - xa) + lane;            // lane's col in stage [0..70]
    bool xok = ((unsigned)x < 1024u);
    float thr = thr_p[0];
    const float NEG = -__builtin_huge_valf();

    __shared__ _Float16 stageh[176 * 80]; // 27.5 KB -> 4 blocks/CU

    int jlo = jlo_t[zc], jhi = jhi_t[zc];
    int istart = jlo > 0 ? jlo - 1 : 0;
    int iend = (jhi + 2 < 50) ? jhi + 2 : 50;

    float gprev[10], A[8], B[8], Dprev[8];
#pragma unroll
    for (int k = 0; k < 10; ++k) gprev[k] = 0.f;
#pragma unroll
    for (int k = 0; k < 8; ++k) { A[k] = NEG; B[k] = NEG; Dprev[k] = 0.f; }

    for (int i = istart; i <= iend; ++i) {
        int r = rarr[i];
        const float* __restrict__ w = wp + i * WPSTRIDE;
        const _Float16* __restrict__ planeh = tmpHh + ((size_t)i << 20);
        int mcount = ((2 * r + 17) >> 3) << 3;       // >= 2r+10, mult of 8
        int nrows = mcount + 64;                     // <= 176
        int gy0blk = (ybg << 6) - 1 - r;
        __syncthreads();                             // prev conv reads done
        int nh8 = nrows * 10;                        // 16B chunks (<= 1760)
        for (int e = t; e < nh8; e += 512) {
            int row = e / 10, c = e - row * 10;
            int gy = gy0blk + row;
            int gx = xa + (c << 3);
            half8 v = {(_Float16)0.f, (_Float16)0.f, (_Float16)0.f, (_Float16)0.f,
                       (_Float16)0.f, (_Float16)0.f, (_Float16)0.f, (_Float16)0.f};
            if ((unsigned)gy < 1024u) {
                const _Float16* rp = planeh + ((size_t)gy << 10);
                if ((unsigned)gx <= 1016u) {
                    v = *(const half8*)(rp + gx);
                } else {
#pragma unroll
                    for (int cc = 0; cc < 8; ++cc) {
                        int g = gx + cc;
                        if ((unsigned)g < 1024u) v[cc] = rp[g];
                    }
                }
            }
            *(half8*)(stageh + row * 80 + (c << 3)) = v;
        }
        __syncthreads();                             // stage visible
        float acc[10];
#pragma unroll
        for (int k = 0; k < 10; ++k) acc[k] = 0.f;
        int base = (wv << 3) * 80 + lx;
        for (int m = 0; m < mcount; m += 8) {
            float v[8];
#pragma unroll
            for (int j = 0; j < 8; ++j)
                v[j] = (float)stageh[base + (m + j) * 80];
            FMAG(w, v, m);
        }
        // ---- epilogue for scale i (unchanged) ----
        if (i > istart) {
            int d = i - 1;
            float sg = sigmas[d];
#pragma unroll
            for (int k = 0; k < 10; ++k) {           // DoG; -inf outside image
                int gy = y0u - 1 + k;
                bool ok = xok && ((unsigned)gy < 1024u);
                gprev[k] = ok ? (gprev[k] - acc[k]) * sg : NEG;
            }
            float ym[8];
#pragma unroll
            for (int k = 0; k < 8; ++k)
                ym[k] = fmaxf(fmaxf(gprev[k], gprev[k + 1]), gprev[k + 2]);
            if (d - 1 >= jlo) {                      // emit j = d-1
                float pooled[8];
#pragma unroll
                for (int k = 0; k < 8; ++k) {
                    float pn = fmaxf(B[k], ym[k]);
                    float l  = __shfl_up(pn, 1);
                    float rr = __shfl_down(pn, 1);
                    pooled[k] = fmaxf(fmaxf(l, rr), pn);
                }
                if (xok && lane >= 1 && lane <= 62) {
                    int j = d - 1;
#pragma unroll
                    for (int k = 0; k < 8; ++k) {
                        float lm = fmaxf(pooled[k] + thr, 0.f);
                        float sm = 1.f - lm + Dprev[k] + thr;
                        float* orow = out + (((size_t)j << 20)
                                     + ((size_t)(y0u + k) << 10));
                        __builtin_nontemporal_store(lm, orow + x);
                        __builtin_nontemporal_store(sm, orow + DOG_ELEMS + x);
                    }
                }
            }
#pragma unroll
            for (int k = 0; k < 8; ++k) {
                B[k] = fmaxf(A[k], ym[k]);
                A[k] = ym[k];
                Dprev[k] = gprev[k + 1];             // dog center rows
            }
        }
#pragma unroll
        for (int k = 0; k < 10; ++k) gprev[k] = acc[k];
    }
    if (jhi == 49) {                                 // tail: j=49 (ym_50 = -inf)
        float pooled[8];
#pragma unroll
        for (int k = 0; k < 8; ++k) {
            float pn = B[k];
            float l  = __shfl_up(pn, 1);
            float rr = __shfl_down(pn, 1);
            pooled[k] = fmaxf(fmaxf(l, rr), pn);
        }
        if (xok && lane >= 1 && lane <= 62) {
#pragma unroll
            for (int k = 0; k < 8; ++k) {
                float lm = fmaxf(pooled[k] + thr, 0.f);
                float sm = 1.f - lm + Dprev[k] + thr;
                float* orow = out + (((size_t)49 << 20)
                             + ((size_t)(y0u + k) << 10));
                __builtin_nontemporal_store(lm, orow + x);
                __builtin_nontemporal_store(sm, orow + DOG_ELEMS + x);
            }
        }
    }
}

extern "C" void kernel_launch(void* const* d_in, const int* in_sizes, int n_in,
                              void* d_out, int out_size, void* d_ws, size_t ws_size,
                              hipStream_t stream) {
    const float* input  = (const float*)d_in[0];
    const float* weight = (const float*)d_in[1];
    const float* sigmas = (const float*)d_in[2];
    const float* thr    = (const float*)d_in[3];
    float* out = (float*)d_out;

    int S = 103;
    if (n_in > 1 && in_sizes[1] >= NS) {
        int s2 = in_sizes[1] / NS;
        S = (int)(sqrt((double)s2) + 0.5);
    }

    size_t need = (size_t)NS * PLANE * 2 + (size_t)NS * WPSTRIDE * 4 + 64 * 4 + 256;
    if (ws_size < need) return;   // insufficient scratch -> visible validation failure

    _Float16* tmpHh = (_Float16*)d_ws;                       // 51 fp16 planes (107 MB)
    float* wp   = (float*)((char*)d_ws + (size_t)NS * PLANE * 2);
    int*   rarr = (int*)(wp + NS * WPSTRIDE);                // 51 ints (64 slots)

    dog_prep <<<NS, 128, 0, stream>>>(weight, wp, rarr, S);
    dog_hblur<<<dim3(512, 5), 256, 0, stream>>>(input, tmpHh, wp, rarr);
    dog_fused<<<1408, 512, 0, stream>>>(tmpHh, out, wp, rarr, sigmas, thr);
}

// Round 19
// 371.144 us; speedup vs baseline: 1.2076x; 1.2076x over previous
//
#include <hip/hip_runtime.h>
#include <cmath>

#define NS 51
#define ND 50
#define PLANE 1048576            // 1024*1024 (elements per plane)
#define DOG_ELEMS (ND * PLANE)   // 52428800
#define WPSTRIDE 160             // padded 1-D kernel: 17 zeros | taps | zeros

typedef __attribute__((ext_vector_type(8))) _Float16 half8;

// ---------------- K0: extract normalized 1-D kernels + radii --------------------
__global__ void dog_prep(const float* __restrict__ weight,
                         float* __restrict__ wp,
                         int* __restrict__ rarr, int S) {
    int i = blockIdx.x;
    int t = threadIdx.x;
    int R = (S - 1) >> 1;
    const float* row = weight + ((size_t)i * S + R) * S;   // center row of scale i
    __shared__ float sr[128];
    __shared__ float ssum;
    __shared__ int spad;
    if (t < S) sr[t] = row[t];
    for (int j = t; j < WPSTRIDE; j += blockDim.x) wp[i * WPSTRIDE + j] = 0.f;
    __syncthreads();
    if (t == 0) {
        float sum = 0.f;
        for (int j = 0; j < S; ++j) sum += sr[j];
        int pad = 0;
        while (pad < R && sr[pad] == 0.f) ++pad;
        ssum = sum; spad = pad;
        rarr[i] = R - pad;
    }
    __syncthreads();
    int pad = spad;
    int r = R - pad;
    float inv = 1.f / ssum;
    for (int j = t; j <= 2 * r; j += blockDim.x)
        wp[i * WPSTRIDE + 17 + j] = sr[pad + j] * inv;
}

// ---------------- K1: horizontal blur (R14 structure; fp16 output) --------------
__global__ __launch_bounds__(256) void dog_hblur(
        const float* __restrict__ in, _Float16* __restrict__ tmpHh,
        const float* __restrict__ wp, const int* __restrict__ rarr) {
    const int lo_t[5] = {0, 17, 28, 37, 44};
    const int hi_t[5] = {17, 28, 37, 44, 51};
    int t = threadIdx.x;
    int grp = t >> 7;
    int tl = t & 127;
    int y = (blockIdx.x << 1) | grp;
    int zc = blockIdx.y;
    __shared__ float srow[2][1284];                 // 321 swizzled float4 slots
    const float* inrow = in + ((size_t)y << 10);
    for (int f = tl; f < 286; f += 128) {           // elements 4f-56 .. 4f-53
        int xg = (f << 2) - 56;
        float4 v = make_float4(0.f, 0.f, 0.f, 0.f);
        if (xg >= 0 && xg <= 1020) {
            v = *(const float4*)(inrow + xg);
        } else {
            float vv[4];
#pragma unroll
            for (int c = 0; c < 4; ++c) {
                int g = xg + c;
                vv[c] = ((unsigned)g < 1024u) ? inrow[g] : 0.f;
            }
            v = make_float4(vv[0], vv[1], vv[2], vv[3]);
        }
        int fs = f + (f >> 3);                      // swizzled float4 index
        *(float4*)&srow[grp][fs << 2] = v;
    }
    __syncthreads();
    const float* s = srow[grp];
    for (int i = lo_t[zc]; i < hi_t[zc]; ++i) {
        int r = rarr[i];
        int c0 = 56 - r;
        int d = c0 & 7;
        int c0a = c0 - d;
        const float* __restrict__ w2 = wp + i * WPSTRIDE + 17 - d;
        int mcount = ((2 * r + d + 15) >> 3) << 3;  // >= 2r+d+8, mult of 8
        float acc[8];
#pragma unroll
        for (int k = 0; k < 8; ++k) acc[k] = 0.f;
        int ft = (c0a >> 2) + (tl << 1);            // base float4 index
        for (int m = 0; m < mcount; m += 8) {
            int f  = ft + (m >> 2);
            int fa = f + (f >> 3);
            int fb = (f + 1) + ((f + 1) >> 3);
            float4 va = *(const float4*)&s[fa << 2];
            float4 vb = *(const float4*)&s[fb << 2];
            float v[8] = {va.x, va.y, va.z, va.w, vb.x, vb.y, vb.z, vb.w};
#pragma unroll
            for (int j2 = 0; j2 < 8; ++j2)
#pragma unroll
                for (int k = 0; k < 8; ++k)
                    acc[k] = fmaf(w2[m + j2 - k], v[j2], acc[k]);
        }
        _Float16* o = tmpHh + (((size_t)i) << 20) + ((size_t)y << 10) + (tl << 3);
        half8 h;
#pragma unroll
        for (int k = 0; k < 8; ++k) h[k] = (_Float16)acc[k];
        *(half8*)o = h;                             // 16B store
    }
}

// ---------------- K2: fused vconv + DoG + 3x3x3 pool + epilogue -----------------
// R18 with ONE change: launch bounds back to (512,6) — the (512,8) bound set a
// 64-VGPR cap and the compiler spilled ~60 live floats to scratch (R18: VGPR 32,
// WRITE 828 MB). At (512,6) cap ~85 VGPR: no spill; occupancy is then resource-
// determined: LDS 27.5 KB allows 5 blocks/CU, wave slots allow 4 -> 4 blocks/CU
// (32 waves), vs 3 for the fp32 version. fp16 payoff without the spill tax.

#define FMAG(W, V, MM) do {                                                       \
_Pragma("unroll")                                                                 \
    for (int j_ = 0; j_ < 8; ++j_)                                                \
_Pragma("unroll")                                                                 \
        for (int k_ = 0; k_ < 10; ++k_)                                           \
            acc[k_] = fmaf((W)[17 + (MM) + j_ - k_], V[j_], acc[k_]);             \
    } while (0)

__global__ __launch_bounds__(512, 6) void dog_fused(
        const _Float16* __restrict__ tmpHh, float* __restrict__ out,
        const float* __restrict__ wp, const int* __restrict__ rarr,
        const float* __restrict__ sigmas, const float* __restrict__ thr_p) {
    const int jlo_t[5] = {0, 17, 28, 37, 44};
    const int jhi_t[5] = {16, 27, 36, 43, 49};
    int p = blockIdx.x;                   // 0..1407
    int xcd = p & 7;
    int q = p >> 3;                       // 0..175
    int c8 = q >> 4;                      // 0..10
    int ybg = q & 15;                     // 0..15  (same-XCD consecutive y-blocks)
    int combo = (c8 << 3) | xcd;          // 0..87
    if (combo >= 85) return;              // pad blocks
    int wx = combo % 17;                  // 0..16
    int zc = combo / 17;                  // 0..4
    int t = threadIdx.x;
    int lane = t & 63;
    int wv = t >> 6;                      // 0..7
    int y0u = __builtin_amdgcn_readfirstlane((ybg << 6) + (wv << 3));
    int x0 = wx * 62 - 1;
    int x = x0 + lane;                    // -1 .. 1054
    int xa = x0 & ~7;                     // 16B-aligned stage base col (halves)
    int lx = (x0 - xa) + lane;            // lane's col in stage [0..70]
    bool xok = ((unsigned)x < 1024u);
    float thr = thr_p[0];
    const float NEG = -__builtin_huge_valf();

    __shared__ _Float16 stageh[176 * 80]; // 27.5 KB

    int jlo = jlo_t[zc], jhi = jhi_t[zc];
    int istart = jlo > 0 ? jlo - 1 : 0;
    int iend = (jhi + 2 < 50) ? jhi + 2 : 50;

    float gprev[10], A[8], B[8], Dprev[8];
#pragma unroll
    for (int k = 0; k < 10; ++k) gprev[k] = 0.f;
#pragma unroll
    for (int k = 0; k < 8; ++k) { A[k] = NEG; B[k] = NEG; Dprev[k] = 0.f; }

    for (int i = istart; i <= iend; ++i) {
        int r = rarr[i];
        const float* __restrict__ w = wp + i * WPSTRIDE;
        const _Float16* __restrict__ planeh = tmpHh + ((size_t)i << 20);
        int mcount = ((2 * r + 17) >> 3) << 3;       // >= 2r+10, mult of 8
        int nrows = mcount + 64;                     // <= 176
        int gy0blk = (ybg << 6) - 1 - r;
        __syncthreads();                             // prev conv reads done
        int nh8 = nrows * 10;                        // 16B chunks (<= 1760)
        for (int e = t; e < nh8; e += 512) {
            int row = e / 10, c = e - row * 10;
            int gy = gy0blk + row;
            int gx = xa + (c << 3);
            half8 v = {(_Float16)0.f, (_Float16)0.f, (_Float16)0.f, (_Float16)0.f,
                       (_Float16)0.f, (_Float16)0.f, (_Float16)0.f, (_Float16)0.f};
            if ((unsigned)gy < 1024u) {
                const _Float16* rp = planeh + ((size_t)gy << 10);
                if ((unsigned)gx <= 1016u) {
                    v = *(const half8*)(rp + gx);
                } else {
#pragma unroll
                    for (int cc = 0; cc < 8; ++cc) {
                        int g = gx + cc;
                        if ((unsigned)g < 1024u) v[cc] = rp[g];
                    }
                }
            }
            *(half8*)(stageh + row * 80 + (c << 3)) = v;
        }
        __syncthreads();                             // stage visible
        float acc[10];
#pragma unroll
        for (int k = 0; k < 10; ++k) acc[k] = 0.f;
        int base = (wv << 3) * 80 + lx;
        for (int m = 0; m < mcount; m += 8) {
            float v[8];
#pragma unroll
            for (int j = 0; j < 8; ++j)
                v[j] = (float)stageh[base + (m + j) * 80];
            FMAG(w, v, m);
        }
        // ---- epilogue for scale i (unchanged) ----
        if (i > istart) {
            int d = i - 1;
            float sg = sigmas[d];
#pragma unroll
            for (int k = 0; k < 10; ++k) {           // DoG; -inf outside image
                int gy = y0u - 1 + k;
                bool ok = xok && ((unsigned)gy < 1024u);
                gprev[k] = ok ? (gprev[k] - acc[k]) * sg : NEG;
            }
            float ym[8];
#pragma unroll
            for (int k = 0; k < 8; ++k)
                ym[k] = fmaxf(fmaxf(gprev[k], gprev[k + 1]), gprev[k + 2]);
            if (d - 1 >= jlo) {                      // emit j = d-1
                float pooled[8];
#pragma unroll
                for (int k = 0; k < 8; ++k) {
                    float pn = fmaxf(B[k], ym[k]);
                    float l  = __shfl_up(pn, 1);
                    float rr = __shfl_down(pn, 1);
                    pooled[k] = fmaxf(fmaxf(l, rr), pn);
                }
                if (xok && lane >= 1 && lane <= 62) {
                    int j = d - 1;
#pragma unroll
                    for (int k = 0; k < 8; ++k) {
                        float lm = fmaxf(pooled[k] + thr, 0.f);
                        float sm = 1.f - lm + Dprev[k] + thr;
                        float* orow = out + (((size_t)j << 20)
                                     + ((size_t)(y0u + k) << 10));
                        __builtin_nontemporal_store(lm, orow + x);
                        __builtin_nontemporal_store(sm, orow + DOG_ELEMS + x);
                    }
                }
            }
#pragma unroll
            for (int k = 0; k < 8; ++k) {
                B[k] = fmaxf(A[k], ym[k]);
                A[k] = ym[k];
                Dprev[k] = gprev[k + 1];             // dog center rows
            }
        }
#pragma unroll
        for (int k = 0; k < 10; ++k) gprev[k] = acc[k];
    }
    if (jhi == 49) {                                 // tail: j=49 (ym_50 = -inf)
        float pooled[8];
#pragma unroll
        for (int k = 0; k < 8; ++k) {
            float pn = B[k];
            float l  = __shfl_up(pn, 1);
            float rr = __shfl_down(pn, 1);
            pooled[k] = fmaxf(fmaxf(l, rr), pn);
        }
        if (xok && lane >= 1 && lane <= 62) {
#pragma unroll
            for (int k = 0; k < 8; ++k) {
                float lm = fmaxf(pooled[k] + thr, 0.f);
                float sm = 1.f - lm + Dprev[k] + thr;
                float* orow = out + (((size_t)49 << 20)
                             + ((size_t)(y0u + k) << 10));
                __builtin_nontemporal_store(lm, orow + x);
                __builtin_nontemporal_store(sm, orow + DOG_ELEMS + x);
            }
        }
    }
}

extern "C" void kernel_launch(void* const* d_in, const int* in_sizes, int n_in,
                              void* d_out, int out_size, void* d_ws, size_t ws_size,
                              hipStream_t stream) {
    const float* input  = (const float*)d_in[0];
    const float* weight = (const float*)d_in[1];
    const float* sigmas = (const float*)d_in[2];
    const float* thr    = (const float*)d_in[3];
    float* out = (float*)d_out;

    int S = 103;
    if (n_in > 1 && in_sizes[1] >= NS) {
        int s2 = in_sizes[1] / NS;
        S = (int)(sqrt((double)s2) + 0.5);
    }

    size_t need = (size_t)NS * PLANE * 2 + (size_t)NS * WPSTRIDE * 4 + 64 * 4 + 256;
    if (ws_size < need) return;   // insufficient scratch -> visible validation failure

    _Float16* tmpHh = (_Float16*)d_ws;                       // 51 fp16 planes (107 MB)
    float* wp   = (float*)((char*)d_ws + (size_t)NS * PLANE * 2);
    int*   rarr = (int*)(wp + NS * WPSTRIDE);                // 51 ints (64 slots)

    dog_prep <<<NS, 128, 0, stream>>>(weight, wp, rarr, S);
    dog_hblur<<<dim3(512, 5), 256, 0, stream>>>(input, tmpHh, wp, rarr);
    dog_fused<<<1408, 512, 0, stream>>>(tmpHh, out, wp, rarr, sigmas, thr);
}

// Round 20
// 364.233 us; speedup vs baseline: 1.2305x; 1.0190x over previous
//
#include <hip/hip_runtime.h>
#include <cmath>

#define NS 51
#define ND 50
#define PLANE 1048576            // 1024*1024 (elements per plane)
#define DOG_ELEMS (ND * PLANE)   // 52428800
#define WPSTRIDE 160             // padded 1-D kernel: 17 zeros | taps | zeros

typedef __attribute__((ext_vector_type(8))) _Float16 half8;
typedef __attribute__((ext_vector_type(2))) _Float16 half2_t;

// ---------------- K0: extract normalized 1-D kernels + radii --------------------
__global__ void dog_prep(const float* __restrict__ weight,
                         float* __restrict__ wp,
                         int* __restrict__ rarr, int S) {
    int i = blockIdx.x;
    int t = threadIdx.x;
    int R = (S - 1) >> 1;
    const float* row = weight + ((size_t)i * S + R) * S;   // center row of scale i
    __shared__ float sr[128];
    __shared__ float ssum;
    __shared__ int spad;
    if (t < S) sr[t] = row[t];
    for (int j = t; j < WPSTRIDE; j += blockDim.x) wp[i * WPSTRIDE + j] = 0.f;
    __syncthreads();
    if (t == 0) {
        float sum = 0.f;
        for (int j = 0; j < S; ++j) sum += sr[j];
        int pad = 0;
        while (pad < R && sr[pad] == 0.f) ++pad;
        ssum = sum; spad = pad;
        rarr[i] = R - pad;
    }
    __syncthreads();
    int pad = spad;
    int r = R - pad;
    float inv = 1.f / ssum;
    for (int j = t; j <= 2 * r; j += blockDim.x)
        wp[i * WPSTRIDE + 17 + j] = sr[pad + j] * inv;
}

// ---------------- K1: horizontal blur (unchanged from R19) ----------------------
__global__ __launch_bounds__(256) void dog_hblur(
        const float* __restrict__ in, _Float16* __restrict__ tmpHh,
        const float* __restrict__ wp, const int* __restrict__ rarr) {
    const int lo_t[5] = {0, 17, 28, 37, 44};
    const int hi_t[5] = {17, 28, 37, 44, 51};
    int t = threadIdx.x;
    int grp = t >> 7;
    int tl = t & 127;
    int y = (blockIdx.x << 1) | grp;
    int zc = blockIdx.y;
    __shared__ float srow[2][1284];                 // 321 swizzled float4 slots
    const float* inrow = in + ((size_t)y << 10);
    for (int f = tl; f < 286; f += 128) {           // elements 4f-56 .. 4f-53
        int xg = (f << 2) - 56;
        float4 v = make_float4(0.f, 0.f, 0.f, 0.f);
        if (xg >= 0 && xg <= 1020) {
            v = *(const float4*)(inrow + xg);
        } else {
            float vv[4];
#pragma unroll
            for (int c = 0; c < 4; ++c) {
                int g = xg + c;
                vv[c] = ((unsigned)g < 1024u) ? inrow[g] : 0.f;
            }
            v = make_float4(vv[0], vv[1], vv[2], vv[3]);
        }
        int fs = f + (f >> 3);                      // swizzled float4 index
        *(float4*)&srow[grp][fs << 2] = v;
    }
    __syncthreads();
    const float* s = srow[grp];
    for (int i = lo_t[zc]; i < hi_t[zc]; ++i) {
        int r = rarr[i];
        int c0 = 56 - r;
        int d = c0 & 7;
        int c0a = c0 - d;
        const float* __restrict__ w2 = wp + i * WPSTRIDE + 17 - d;
        int mcount = ((2 * r + d + 15) >> 3) << 3;  // >= 2r+d+8, mult of 8
        float acc[8];
#pragma unroll
        for (int k = 0; k < 8; ++k) acc[k] = 0.f;
        int ft = (c0a >> 2) + (tl << 1);            // base float4 index
        for (int m = 0; m < mcount; m += 8) {
            int f  = ft + (m >> 2);
            int fa = f + (f >> 3);
            int fb = (f + 1) + ((f + 1) >> 3);
            float4 va = *(const float4*)&s[fa << 2];
            float4 vb = *(const float4*)&s[fb << 2];
            float v[8] = {va.x, va.y, va.z, va.w, vb.x, vb.y, vb.z, vb.w};
#pragma unroll
            for (int j2 = 0; j2 < 8; ++j2)
#pragma unroll
                for (int k = 0; k < 8; ++k)
                    acc[k] = fmaf(w2[m + j2 - k], v[j2], acc[k]);
        }
        _Float16* o = tmpHh + (((size_t)i) << 20) + ((size_t)y << 10) + (tl << 3);
        half8 h;
#pragma unroll
        for (int k = 0; k < 8; ++k) h[k] = (_Float16)acc[k];
        *(half8*)o = h;                             // 16B store
    }
}

// ---------------- K2: fused vconv + DoG + 3x3x3 pool + epilogue -----------------
// R19 with ONE change: row-pair interleaved LDS stage [row/2][col][row%2].
// Conv m-step reads 4x ds_read_b32 (each = rows m+2jj, m+2jj+1 at col lx)
// instead of 8x ds_read_u16 -> LDS-read instrs halve (lanes consecutive dwords,
// 2-way free). Staging: load 2 global half8 rows, interleave in regs, write
// 2x b128. Same LDS bytes (28160), geometry, epilogue.

#define FMAG(W, V, MM) do {                                                       \
_Pragma("unroll")                                                                 \
    for (int j_ = 0; j_ < 8; ++j_)                                                \
_Pragma("unroll")                                                                 \
        for (int k_ = 0; k_ < 10; ++k_)                                           \
            acc[k_] = fmaf((W)[17 + (MM) + j_ - k_], V[j_], acc[k_]);             \
    } while (0)

__global__ __launch_bounds__(512, 6) void dog_fused(
        const _Float16* __restrict__ tmpHh, float* __restrict__ out,
        const float* __restrict__ wp, const int* __restrict__ rarr,
        const float* __restrict__ sigmas, const float* __restrict__ thr_p) {
    const int jlo_t[5] = {0, 17, 28, 37, 44};
    const int jhi_t[5] = {16, 27, 36, 43, 49};
    int p = blockIdx.x;                   // 0..1407
    int xcd = p & 7;
    int q = p >> 3;                       // 0..175
    int c8 = q >> 4;                      // 0..10
    int ybg = q & 15;                     // 0..15  (same-XCD consecutive y-blocks)
    int combo = (c8 << 3) | xcd;          // 0..87
    if (combo >= 85) return;              // pad blocks
    int wx = combo % 17;                  // 0..16
    int zc = combo / 17;                  // 0..4
    int t = threadIdx.x;
    int lane = t & 63;
    int wv = t >> 6;                      // 0..7
    int y0u = __builtin_amdgcn_readfirstlane((ybg << 6) + (wv << 3));
    int x0 = wx * 62 - 1;
    int x = x0 + lane;                    // -1 .. 1054
    int xa = x0 & ~7;                     // 16B-aligned stage base col (halves)
    int lx = (x0 - xa) + lane;            // lane's col in stage [0..70]
    bool xok = ((unsigned)x < 1024u);
    float thr = thr_p[0];
    const float NEG = -__builtin_huge_valf();

    // [88 row-pairs][80 cols][2] fp16 = 28160 B
    __shared__ _Float16 stageh[88 * 160];

    int jlo = jlo_t[zc], jhi = jhi_t[zc];
    int istart = jlo > 0 ? jlo - 1 : 0;
    int iend = (jhi + 2 < 50) ? jhi + 2 : 50;

    float gprev[10], A[8], B[8], Dprev[8];
#pragma unroll
    for (int k = 0; k < 10; ++k) gprev[k] = 0.f;
#pragma unroll
    for (int k = 0; k < 8; ++k) { A[k] = NEG; B[k] = NEG; Dprev[k] = 0.f; }

    for (int i = istart; i <= iend; ++i) {
        int r = rarr[i];
        const float* __restrict__ w = wp + i * WPSTRIDE;
        const _Float16* __restrict__ planeh = tmpHh + ((size_t)i << 20);
        int mcount = ((2 * r + 17) >> 3) << 3;       // >= 2r+10, mult of 8
        int nrp = (mcount + 64) >> 1;                // row-pairs (<= 88)
        int gy0blk = (ybg << 6) - 1 - r;
        __syncthreads();                             // prev conv reads done
        int nch = nrp * 10;                          // chunks: (row-pair, 8 cols)
        for (int e = t; e < nch; e += 512) {
            int rp = e / 10, c = e - rp * 10;
            int gyA = gy0blk + (rp << 1);
            int gyB = gyA + 1;
            int gx = xa + (c << 3);
            half8 va = {(_Float16)0.f, (_Float16)0.f, (_Float16)0.f, (_Float16)0.f,
                        (_Float16)0.f, (_Float16)0.f, (_Float16)0.f, (_Float16)0.f};
            half8 vb = va;
            bool inx = ((unsigned)gx <= 1016u);
            if ((unsigned)gyA < 1024u) {
                const _Float16* rp_ = planeh + ((size_t)gyA << 10);
                if (inx) va = *(const half8*)(rp_ + gx);
                else {
#pragma unroll
                    for (int cc = 0; cc < 8; ++cc) {
                        int g = gx + cc;
                        if ((unsigned)g < 1024u) va[cc] = rp_[g];
                    }
                }
            }
            if ((unsigned)gyB < 1024u) {
                const _Float16* rp_ = planeh + ((size_t)gyB << 10);
                if (inx) vb = *(const half8*)(rp_ + gx);
                else {
#pragma unroll
                    for (int cc = 0; cc < 8; ++cc) {
                        int g = gx + cc;
                        if ((unsigned)g < 1024u) vb[cc] = rp_[g];
                    }
                }
            }
            half8 w0, w1;                            // interleave rows A,B
            w0[0] = va[0]; w0[1] = vb[0]; w0[2] = va[1]; w0[3] = vb[1];
            w0[4] = va[2]; w0[5] = vb[2]; w0[6] = va[3]; w0[7] = vb[3];
            w1[0] = va[4]; w1[1] = vb[4]; w1[2] = va[5]; w1[3] = vb[5];
            w1[4] = va[6]; w1[5] = vb[6]; w1[6] = va[7]; w1[7] = vb[7];
            _Float16* dst = stageh + rp * 160 + (c << 4);
            *(half8*)dst       = w0;
            *(half8*)(dst + 8) = w1;
        }
        __syncthreads();                             // stage visible
        float acc[10];
#pragma unroll
        for (int k = 0; k < 10; ++k) acc[k] = 0.f;
        int b0 = (wv << 2) * 160 + (lx << 1);        // row-pair 4wv, col lx
        for (int m = 0; m < mcount; m += 8) {
            int ib = b0 + (m >> 1) * 160;
            float v[8];
#pragma unroll
            for (int jj = 0; jj < 4; ++jj) {
                half2_t h = *(const half2_t*)&stageh[ib + jj * 160];
                v[2 * jj]     = (float)h[0];
                v[2 * jj + 1] = (float)h[1];
            }
            FMAG(w, v, m);
        }
        // ---- epilogue for scale i (unchanged) ----
        if (i > istart) {
            int d = i - 1;
            float sg = sigmas[d];
#pragma unroll
            for (int k = 0; k < 10; ++k) {           // DoG; -inf outside image
                int gy = y0u - 1 + k;
                bool ok = xok && ((unsigned)gy < 1024u);
                gprev[k] = ok ? (gprev[k] - acc[k]) * sg : NEG;
            }
            float ym[8];
#pragma unroll
            for (int k = 0; k < 8; ++k)
                ym[k] = fmaxf(fmaxf(gprev[k], gprev[k + 1]), gprev[k + 2]);
            if (d - 1 >= jlo) {                      // emit j = d-1
                float pooled[8];
#pragma unroll
                for (int k = 0; k < 8; ++k) {
                    float pn = fmaxf(B[k], ym[k]);
                    float l  = __shfl_up(pn, 1);
                    float rr = __shfl_down(pn, 1);
                    pooled[k] = fmaxf(fmaxf(l, rr), pn);
                }
                if (xok && lane >= 1 && lane <= 62) {
                    int j = d - 1;
#pragma unroll
                    for (int k = 0; k < 8; ++k) {
                        float lm = fmaxf(pooled[k] + thr, 0.f);
                        float sm = 1.f - lm + Dprev[k] + thr;
                        float* orow = out + (((size_t)j << 20)
                                     + ((size_t)(y0u + k) << 10));
                        __builtin_nontemporal_store(lm, orow + x);
                        __builtin_nontemporal_store(sm, orow + DOG_ELEMS + x);
                    }
                }
            }
#pragma unroll
            for (int k = 0; k < 8; ++k) {
                B[k] = fmaxf(A[k], ym[k]);
                A[k] = ym[k];
                Dprev[k] = gprev[k + 1];             // dog center rows
            }
        }
#pragma unroll
        for (int k = 0; k < 10; ++k) gprev[k] = acc[k];
    }
    if (jhi == 49) {                                 // tail: j=49 (ym_50 = -inf)
        float pooled[8];
#pragma unroll
        for (int k = 0; k < 8; ++k) {
            float pn = B[k];
            float l  = __shfl_up(pn, 1);
            float rr = __shfl_down(pn, 1);
            pooled[k] = fmaxf(fmaxf(l, rr), pn);
        }
        if (xok && lane >= 1 && lane <= 62) {
#pragma unroll
            for (int k = 0; k < 8; ++k) {
                float lm = fmaxf(pooled[k] + thr, 0.f);
                float sm = 1.f - lm + Dprev[k] + thr;
                float* orow = out + (((size_t)49 << 20)
                             + ((size_t)(y0u + k) << 10));
                __builtin_nontemporal_store(lm, orow + x);
                __builtin_nontemporal_store(sm, orow + DOG_ELEMS + x);
            }
        }
    }
}

extern "C" void kernel_launch(void* const* d_in, const int* in_sizes, int n_in,
                              void* d_out, int out_size, void* d_ws, size_t ws_size,
                              hipStream_t stream) {
    const float* input  = (const float*)d_in[0];
    const float* weight = (const float*)d_in[1];
    const float* sigmas = (const float*)d_in[2];
    const float* thr    = (const float*)d_in[3];
    float* out = (float*)d_out;

    int S = 103;
    if (n_in > 1 && in_sizes[1] >= NS) {
        int s2 = in_sizes[1] / NS;
        S = (int)(sqrt((double)s2) + 0.5);
    }

    size_t need = (size_t)NS * PLANE * 2 + (size_t)NS * WPSTRIDE * 4 + 64 * 4 + 256;
    if (ws_size < need) return;   // insufficient scratch -> visible validation failure

    _Float16* tmpHh = (_Float16*)d_ws;                       // 51 fp16 planes (107 MB)
    float* wp   = (float*)((char*)d_ws + (size_t)NS * PLANE * 2);
    int*   rarr = (int*)(wp + NS * WPSTRIDE);                // 51 ints (64 slots)

    dog_prep <<<NS, 128, 0, stream>>>(weight, wp, rarr, S);
    dog_hblur<<<dim3(512, 5), 256, 0, stream>>>(input, tmpHh, wp, rarr);
    dog_fused<<<1408, 512, 0, stream>>>(tmpHh, out, wp, rarr, sigmas, thr);
}

// Round 21
// 352.522 us; speedup vs baseline: 1.2714x; 1.0332x over previous
//
#include <hip/hip_runtime.h>
#include <cmath>

#define NS 51
#define ND 50
#define PLANE 1048576            // 1024*1024 (elements per plane)
#define DOG_ELEMS (ND * PLANE)   // 52428800
#define WPSTRIDE 160             // padded fp32 1-D kernel: 17 zeros | taps | zeros
#define WPAIRS 80                // fp16 pair slots per scale (base offset 8)

typedef __attribute__((ext_vector_type(8))) _Float16 half8;
typedef __attribute__((ext_vector_type(2))) _Float16 half2_t;

// ---------------- K0: 1-D kernels (fp32) + fp16 packed pair tables + radii ------
__global__ void dog_prep(const float* __restrict__ weight,
                         float* __restrict__ wp,
                         half2_t* __restrict__ whA,
                         half2_t* __restrict__ whB,
                         int* __restrict__ rarr, int S) {
    int i = blockIdx.x;
    int t = threadIdx.x;
    int R = (S - 1) >> 1;
    const float* row = weight + ((size_t)i * S + R) * S;   // center row of scale i
    __shared__ float sr[128];
    __shared__ float ssum;
    __shared__ int spad;
    if (t < S) sr[t] = row[t];
    for (int j = t; j < WPSTRIDE; j += blockDim.x) wp[i * WPSTRIDE + j] = 0.f;
    __syncthreads();
    if (t == 0) {
        float sum = 0.f;
        for (int j = 0; j < S; ++j) sum += sr[j];
        int pad = 0;
        while (pad < R && sr[pad] == 0.f) ++pad;
        ssum = sum; spad = pad;
        rarr[i] = R - pad;
    }
    __syncthreads();
    int pad = spad;
    int r = R - pad;
    float inv = 1.f / ssum;
    for (int j = t; j <= 2 * r; j += blockDim.x)
        wp[i * WPSTRIDE + 17 + j] = sr[pad + j] * inv;
    // fp16 pair tables: logical wh[j] = taps[j] for j in [0,2r], else 0.
    // whA[8+tp] = (wh[2tp], wh[2tp+1]); whB[8+tp] = (wh[2tp+1], wh[2tp+2]).
    for (int tt = t; tt < WPAIRS; tt += blockDim.x) {
        int j0 = 2 * (tt - 8);
        float a0 = (j0 >= 0 && j0 <= 2 * r) ? sr[pad + j0] * inv : 0.f;
        float a1 = (j0 + 1 >= 0 && j0 + 1 <= 2 * r) ? sr[pad + j0 + 1] * inv : 0.f;
        float a2 = (j0 + 2 >= 0 && j0 + 2 <= 2 * r) ? sr[pad + j0 + 2] * inv : 0.f;
        half2_t pa, pb;
        pa[0] = (_Float16)a0; pa[1] = (_Float16)a1;
        pb[0] = (_Float16)a1; pb[1] = (_Float16)a2;
        whA[i * WPAIRS + tt] = pa;
        whB[i * WPAIRS + tt] = pb;
    }
}

// ---------------- K1: horizontal blur (unchanged from R19/R20) ------------------
__global__ __launch_bounds__(256) void dog_hblur(
        const float* __restrict__ in, _Float16* __restrict__ tmpHh,
        const float* __restrict__ wp, const int* __restrict__ rarr) {
    const int lo_t[5] = {0, 17, 28, 37, 44};
    const int hi_t[5] = {17, 28, 37, 44, 51};
    int t = threadIdx.x;
    int grp = t >> 7;
    int tl = t & 127;
    int y = (blockIdx.x << 1) | grp;
    int zc = blockIdx.y;
    __shared__ float srow[2][1284];                 // 321 swizzled float4 slots
    const float* inrow = in + ((size_t)y << 10);
    for (int f = tl; f < 286; f += 128) {           // elements 4f-56 .. 4f-53
        int xg = (f << 2) - 56;
        float4 v = make_float4(0.f, 0.f, 0.f, 0.f);
        if (xg >= 0 && xg <= 1020) {
            v = *(const float4*)(inrow + xg);
        } else {
            float vv[4];
#pragma unroll
            for (int c = 0; c < 4; ++c) {
                int g = xg + c;
                vv[c] = ((unsigned)g < 1024u) ? inrow[g] : 0.f;
            }
            v = make_float4(vv[0], vv[1], vv[2], vv[3]);
        }
        int fs = f + (f >> 3);                      // swizzled float4 index
        *(float4*)&srow[grp][fs << 2] = v;
    }
    __syncthreads();
    const float* s = srow[grp];
    for (int i = lo_t[zc]; i < hi_t[zc]; ++i) {
        int r = rarr[i];
        int c0 = 56 - r;
        int d = c0 & 7;
        int c0a = c0 - d;
        const float* __restrict__ w2 = wp + i * WPSTRIDE + 17 - d;
        int mcount = ((2 * r + d + 15) >> 3) << 3;  // >= 2r+d+8, mult of 8
        float acc[8];
#pragma unroll
        for (int k = 0; k < 8; ++k) acc[k] = 0.f;
        int ft = (c0a >> 2) + (tl << 1);            // base float4 index
        for (int m = 0; m < mcount; m += 8) {
            int f  = ft + (m >> 2);
            int fa = f + (f >> 3);
            int fb = (f + 1) + ((f + 1) >> 3);
            float4 va = *(const float4*)&s[fa << 2];
            float4 vb = *(const float4*)&s[fb << 2];
            float v[8] = {va.x, va.y, va.z, va.w, vb.x, vb.y, vb.z, vb.w};
#pragma unroll
            for (int j2 = 0; j2 < 8; ++j2)
#pragma unroll
                for (int k = 0; k < 8; ++k)
                    acc[k] = fmaf(w2[m + j2 - k], v[j2], acc[k]);
        }
        _Float16* o = tmpHh + (((size_t)i) << 20) + ((size_t)y << 10) + (tl << 3);
        half8 h;
#pragma unroll
        for (int k = 0; k < 8; ++k) h[k] = (_Float16)acc[k];
        *(half8*)o = h;                             // 16B store
    }
}

// ---------------- K2: fused vconv + DoG + 3x3x3 pool + epilogue -----------------
// R20 with ONE change: conv inner loop uses v_dot2_f32_f16. The row-pair
// interleaved stage already yields packed (row m, row m+1) half2 per b32 read;
// weight pairs (w[a],w[a+1]) come from fp16 tables whA (a even) / whB (a odd),
// selected statically by k parity with uniform index. Per 8-tap m-step:
// 4 ds_read_b32 + 40 fdot2 — replaces 80 fmaf + 8 cvt.

__global__ __launch_bounds__(512, 6) void dog_fused(
        const _Float16* __restrict__ tmpHh, float* __restrict__ out,
        const half2_t* __restrict__ whA, const half2_t* __restrict__ whB,
        const int* __restrict__ rarr,
        const float* __restrict__ sigmas, const float* __restrict__ thr_p) {
    const int jlo_t[5] = {0, 17, 28, 37, 44};
    const int jhi_t[5] = {16, 27, 36, 43, 49};
    int p = blockIdx.x;                   // 0..1407
    int xcd = p & 7;
    int q = p >> 3;                       // 0..175
    int c8 = q >> 4;                      // 0..10
    int ybg = q & 15;                     // 0..15  (same-XCD consecutive y-blocks)
    int combo = (c8 << 3) | xcd;          // 0..87
    if (combo >= 85) return;              // pad blocks
    int wx = combo % 17;                  // 0..16
    int zc = combo / 17;                  // 0..4
    int t = threadIdx.x;
    int lane = t & 63;
    int wv = t >> 6;                      // 0..7
    int y0u = __builtin_amdgcn_readfirstlane((ybg << 6) + (wv << 3));
    int x0 = wx * 62 - 1;
    int x = x0 + lane;                    // -1 .. 1054
    int xa = x0 & ~7;                     // 16B-aligned stage base col (halves)
    int lx = (x0 - xa) + lane;            // lane's col in stage [0..70]
    bool xok = ((unsigned)x < 1024u);
    float thr = thr_p[0];
    const float NEG = -__builtin_huge_valf();

    // [88 row-pairs][80 cols][2] fp16 = 28160 B
    __shared__ _Float16 stageh[88 * 160];

    int jlo = jlo_t[zc], jhi = jhi_t[zc];
    int istart = jlo > 0 ? jlo - 1 : 0;
    int iend = (jhi + 2 < 50) ? jhi + 2 : 50;

    float gprev[10], A[8], B[8], Dprev[8];
#pragma unroll
    for (int k = 0; k < 10; ++k) gprev[k] = 0.f;
#pragma unroll
    for (int k = 0; k < 8; ++k) { A[k] = NEG; B[k] = NEG; Dprev[k] = 0.f; }

    for (int i = istart; i <= iend; ++i) {
        int r = rarr[i];
        const half2_t* __restrict__ wA = whA + i * WPAIRS + 8;
        const half2_t* __restrict__ wB = whB + i * WPAIRS + 8;
        const _Float16* __restrict__ planeh = tmpHh + ((size_t)i << 20);
        int mcount = ((2 * r + 17) >> 3) << 3;       // >= 2r+10, mult of 8
        int nrp = (mcount + 64) >> 1;                // row-pairs (<= 88)
        int gy0blk = (ybg << 6) - 1 - r;
        __syncthreads();                             // prev conv reads done
        int nch = nrp * 10;                          // chunks: (row-pair, 8 cols)
        for (int e = t; e < nch; e += 512) {
            int rp = e / 10, c = e - rp * 10;
            int gyA = gy0blk + (rp << 1);
            int gyB = gyA + 1;
            int gx = xa + (c << 3);
            half8 va = {(_Float16)0.f, (_Float16)0.f, (_Float16)0.f, (_Float16)0.f,
                        (_Float16)0.f, (_Float16)0.f, (_Float16)0.f, (_Float16)0.f};
            half8 vb = va;
            bool inx = ((unsigned)gx <= 1016u);
            if ((unsigned)gyA < 1024u) {
                const _Float16* rp_ = planeh + ((size_t)gyA << 10);
                if (inx) va = *(const half8*)(rp_ + gx);
                else {
#pragma unroll
                    for (int cc = 0; cc < 8; ++cc) {
                        int g = gx + cc;
                        if ((unsigned)g < 1024u) va[cc] = rp_[g];
                    }
                }
            }
            if ((unsigned)gyB < 1024u) {
                const _Float16* rp_ = planeh + ((size_t)gyB << 10);
                if (inx) vb = *(const half8*)(rp_ + gx);
                else {
#pragma unroll
                    for (int cc = 0; cc < 8; ++cc) {
                        int g = gx + cc;
                        if ((unsigned)g < 1024u) vb[cc] = rp_[g];
                    }
                }
            }
            half8 w0, w1;                            // interleave rows A,B
            w0[0] = va[0]; w0[1] = vb[0]; w0[2] = va[1]; w0[3] = vb[1];
            w0[4] = va[2]; w0[5] = vb[2]; w0[6] = va[3]; w0[7] = vb[3];
            w1[0] = va[4]; w1[1] = vb[4]; w1[2] = va[5]; w1[3] = vb[5];
            w1[4] = va[6]; w1[5] = vb[6]; w1[6] = va[7]; w1[7] = vb[7];
            _Float16* dst = stageh + rp * 160 + (c << 4);
            *(half8*)dst       = w0;
            *(half8*)(dst + 8) = w1;
        }
        __syncthreads();                             // stage visible
        float acc[10];
#pragma unroll
        for (int k = 0; k < 10; ++k) acc[k] = 0.f;
        int b0 = (wv << 2) * 160 + (lx << 1);        // row-pair 4wv, col lx
        for (int m = 0; m < mcount; m += 8) {
            int ib = b0 + (m >> 1) * 160;
            int pb = m >> 1;                         // uniform pair base
            half2_t v[4];
#pragma unroll
            for (int jj = 0; jj < 4; ++jj)
                v[jj] = *(const half2_t*)&stageh[ib + jj * 160];
#pragma unroll
            for (int jj = 0; jj < 4; ++jj)
#pragma unroll
                for (int k = 0; k < 10; ++k) {
                    half2_t wpair = (k & 1) ? wB[pb + jj - ((k + 1) >> 1)]
                                            : wA[pb + jj - (k >> 1)];
                    acc[k] = __builtin_amdgcn_fdot2(v[jj], wpair, acc[k], false);
                }
        }
        // ---- epilogue for scale i (unchanged) ----
        if (i > istart) {
            int d = i - 1;
            float sg = sigmas[d];
#pragma unroll
            for (int k = 0; k < 10; ++k) {           // DoG; -inf outside image
                int gy = y0u - 1 + k;
                bool ok = xok && ((unsigned)gy < 1024u);
                gprev[k] = ok ? (gprev[k] - acc[k]) * sg : NEG;
            }
            float ym[8];
#pragma unroll
            for (int k = 0; k < 8; ++k)
                ym[k] = fmaxf(fmaxf(gprev[k], gprev[k + 1]), gprev[k + 2]);
            if (d - 1 >= jlo) {                      // emit j = d-1
                float pooled[8];
#pragma unroll
                for (int k = 0; k < 8; ++k) {
                    float pn = fmaxf(B[k], ym[k]);
                    float l  = __shfl_up(pn, 1);
                    float rr = __shfl_down(pn, 1);
                    pooled[k] = fmaxf(fmaxf(l, rr), pn);
                }
                if (xok && lane >= 1 && lane <= 62) {
                    int j = d - 1;
#pragma unroll
                    for (int k = 0; k < 8; ++k) {
                        float lm = fmaxf(pooled[k] + thr, 0.f);
                        float sm = 1.f - lm + Dprev[k] + thr;
                        float* orow = out + (((size_t)j << 20)
                                     + ((size_t)(y0u + k) << 10));
                        __builtin_nontemporal_store(lm, orow + x);
                        __builtin_nontemporal_store(sm, orow + DOG_ELEMS + x);
                    }
                }
            }
#pragma unroll
            for (int k = 0; k < 8; ++k) {
                B[k] = fmaxf(A[k], ym[k]);
                A[k] = ym[k];
                Dprev[k] = gprev[k + 1];             // dog center rows
            }
        }
#pragma unroll
        for (int k = 0; k < 10; ++k) gprev[k] = acc[k];
    }
    if (jhi == 49) {                                 // tail: j=49 (ym_50 = -inf)
        float pooled[8];
#pragma unroll
        for (int k = 0; k < 8; ++k) {
            float pn = B[k];
            float l  = __shfl_up(pn, 1);
            float rr = __shfl_down(pn, 1);
            pooled[k] = fmaxf(fmaxf(l, rr), pn);
        }
        if (xok && lane >= 1 && lane <= 62) {
#pragma unroll
            for (int k = 0; k < 8; ++k) {
                float lm = fmaxf(pooled[k] + thr, 0.f);
                float sm = 1.f - lm + Dprev[k] + thr;
                float* orow = out + (((size_t)49 << 20)
                             + ((size_t)(y0u + k) << 10));
                __builtin_nontemporal_store(lm, orow + x);
                __builtin_nontemporal_store(sm, orow + DOG_ELEMS + x);
            }
        }
    }
}

extern "C" void kernel_launch(void* const* d_in, const int* in_sizes, int n_in,
                              void* d_out, int out_size, void* d_ws, size_t ws_size,
                              hipStream_t stream) {
    const float* input  = (const float*)d_in[0];
    const float* weight = (const float*)d_in[1];
    const float* sigmas = (const float*)d_in[2];
    const float* thr    = (const float*)d_in[3];
    float* out = (float*)d_out;

    int S = 103;
    if (n_in > 1 && in_sizes[1] >= NS) {
        int s2 = in_sizes[1] / NS;
        S = (int)(sqrt((double)s2) + 0.5);
    }

    size_t need = (size_t)NS * PLANE * 2 + (size_t)NS * WPSTRIDE * 4
                + 64 * 4 + (size_t)NS * WPAIRS * 4 * 2 + 256;
    if (ws_size < need) return;   // insufficient scratch -> visible validation failure

    _Float16* tmpHh = (_Float16*)d_ws;                       // 51 fp16 planes (107 MB)
    float* wp   = (float*)((char*)d_ws + (size_t)NS * PLANE * 2);
    int*   rarr = (int*)(wp + NS * WPSTRIDE);                // 51 ints (64 slots)
    half2_t* whA = (half2_t*)(rarr + 64);                    // 51*80 pairs
    half2_t* whB = whA + NS * WPAIRS;                        // 51*80 pairs

    dog_prep <<<NS, 128, 0, stream>>>(weight, wp, whA, whB, rarr, S);
    dog_hblur<<<dim3(512, 5), 256, 0, stream>>>(input, tmpHh, wp, rarr);
    dog_fused<<<1408, 512, 0, stream>>>(tmpHh, out, whA, whB, rarr, sigmas, thr);
}

// Round 23
// 351.796 us; speedup vs baseline: 1.2740x; 1.0021x over previous
//
#include <hip/hip_runtime.h>
#include <cmath>

#define NS 51
#define ND 50
#define PLANE 1048576            // 1024*1024 (elements per plane)
#define DOG_ELEMS (ND * PLANE)   // 52428800
#define WPSTRIDE 160             // padded fp32 1-D kernel: 17 zeros | taps | zeros
#define WPAIRS 80                // fp16 pair slots per scale (base offset 8)

typedef __attribute__((ext_vector_type(8))) _Float16 half8;
typedef __attribute__((ext_vector_type(2))) _Float16 half2_t;

// ---------------- K0: 1-D kernels (fp32) + fp16 packed pair tables + radii ------
__global__ void dog_prep(const float* __restrict__ weight,
                         float* __restrict__ wp,
                         half2_t* __restrict__ whA,
                         half2_t* __restrict__ whB,
                         int* __restrict__ rarr, int S) {
    int i = blockIdx.x;
    int t = threadIdx.x;
    int R = (S - 1) >> 1;
    const float* row = weight + ((size_t)i * S + R) * S;   // center row of scale i
    __shared__ float sr[128];
    __shared__ float ssum;
    __shared__ int spad;
    if (t < S) sr[t] = row[t];
    for (int j = t; j < WPSTRIDE; j += blockDim.x) wp[i * WPSTRIDE + j] = 0.f;
    __syncthreads();
    if (t == 0) {
        float sum = 0.f;
        for (int j = 0; j < S; ++j) sum += sr[j];
        int pad = 0;
        while (pad < R && sr[pad] == 0.f) ++pad;
        ssum = sum; spad = pad;
        rarr[i] = R - pad;
    }
    __syncthreads();
    int pad = spad;
    int r = R - pad;
    float inv = 1.f / ssum;
    for (int j = t; j <= 2 * r; j += blockDim.x)
        wp[i * WPSTRIDE + 17 + j] = sr[pad + j] * inv;
    // fp16 pair tables: logical wh[j] = taps[j] for j in [0,2r], else 0.
    // whA[8+tp] = (wh[2tp], wh[2tp+1]); whB[8+tp] = (wh[2tp+1], wh[2tp+2]).
    for (int tt = t; tt < WPAIRS; tt += blockDim.x) {
        int j0 = 2 * (tt - 8);
        float a0 = (j0 >= 0 && j0 <= 2 * r) ? sr[pad + j0] * inv : 0.f;
        float a1 = (j0 + 1 >= 0 && j0 + 1 <= 2 * r) ? sr[pad + j0 + 1] * inv : 0.f;
        float a2 = (j0 + 2 >= 0 && j0 + 2 <= 2 * r) ? sr[pad + j0 + 2] * inv : 0.f;
        half2_t pa, pb;
        pa[0] = (_Float16)a0; pa[1] = (_Float16)a1;
        pb[0] = (_Float16)a1; pb[1] = (_Float16)a2;
        whA[i * WPAIRS + tt] = pa;
        whB[i * WPAIRS + tt] = pb;
    }
}

// ---------------- K1: horizontal blur (R21: fp32 LDS + fmaf ladder) -------------
__global__ __launch_bounds__(256) void dog_hblur(
        const float* __restrict__ in, _Float16* __restrict__ tmpHh,
        const float* __restrict__ wp, const int* __restrict__ rarr) {
    const int lo_t[5] = {0, 17, 28, 37, 44};
    const int hi_t[5] = {17, 28, 37, 44, 51};
    int t = threadIdx.x;
    int grp = t >> 7;
    int tl = t & 127;
    int y = (blockIdx.x << 1) | grp;
    int zc = blockIdx.y;
    __shared__ float srow[2][1284];                 // 321 swizzled float4 slots
    const float* inrow = in + ((size_t)y << 10);
    for (int f = tl; f < 286; f += 128) {           // elements 4f-56 .. 4f-53
        int xg = (f << 2) - 56;
        float4 v = make_float4(0.f, 0.f, 0.f, 0.f);
        if (xg >= 0 && xg <= 1020) {
            v = *(const float4*)(inrow + xg);
        } else {
            float vv[4];
#pragma unroll
            for (int c = 0; c < 4; ++c) {
                int g = xg + c;
                vv[c] = ((unsigned)g < 1024u) ? inrow[g] : 0.f;
            }
            v = make_float4(vv[0], vv[1], vv[2], vv[3]);
        }
        int fs = f + (f >> 3);                      // swizzled float4 index
        *(float4*)&srow[grp][fs << 2] = v;
    }
    __syncthreads();
    const float* s = srow[grp];
    for (int i = lo_t[zc]; i < hi_t[zc]; ++i) {
        int r = rarr[i];
        int c0 = 56 - r;
        int d = c0 & 7;
        int c0a = c0 - d;
        const float* __restrict__ w2 = wp + i * WPSTRIDE + 17 - d;
        int mcount = ((2 * r + d + 15) >> 3) << 3;  // >= 2r+d+8, mult of 8
        float acc[8];
#pragma unroll
        for (int k = 0; k < 8; ++k) acc[k] = 0.f;
        int ft = (c0a >> 2) + (tl << 1);            // base float4 index
        for (int m = 0; m < mcount; m += 8) {
            int f  = ft + (m >> 2);
            int fa = f + (f >> 3);
            int fb = (f + 1) + ((f + 1) >> 3);
            float4 va = *(const float4*)&s[fa << 2];
            float4 vb = *(const float4*)&s[fb << 2];
            float v[8] = {va.x, va.y, va.z, va.w, vb.x, vb.y, vb.z, vb.w};
#pragma unroll
            for (int j2 = 0; j2 < 8; ++j2)
#pragma unroll
                for (int k = 0; k < 8; ++k)
                    acc[k] = fmaf(w2[m + j2 - k], v[j2], acc[k]);
        }
        _Float16* o = tmpHh + (((size_t)i) << 20) + ((size_t)y << 10) + (tl << 3);
        half8 h;
#pragma unroll
        for (int k = 0; k < 8; ++k) h[k] = (_Float16)acc[k];
        *(half8*)o = h;                             // 16B store
    }
}

// ---------------- K2: fused vconv + DoG + 3x3x3 pool + epilogue (R21) -----------
__global__ __launch_bounds__(512, 6) void dog_fused(
        const _Float16* __restrict__ tmpHh, float* __restrict__ out,
        const half2_t* __restrict__ whA, const half2_t* __restrict__ whB,
        const int* __restrict__ rarr,
        const float* __restrict__ sigmas, const float* __restrict__ thr_p) {
    const int jlo_t[5] = {0, 17, 28, 37, 44};
    const int jhi_t[5] = {16, 27, 36, 43, 49};
    int p = blockIdx.x;                   // 0..1407
    int xcd = p & 7;
    int q = p >> 3;                       // 0..175
    int c8 = q >> 4;                      // 0..10
    int ybg = q & 15;                     // 0..15  (same-XCD consecutive y-blocks)
    int combo = (c8 << 3) | xcd;          // 0..87
    if (combo >= 85) return;              // pad blocks
    int wx = combo % 17;                  // 0..16
    int zc = combo / 17;                  // 0..4
    int t = threadIdx.x;
    int lane = t & 63;
    int wv = t >> 6;                      // 0..7
    int y0u = __builtin_amdgcn_readfirstlane((ybg << 6) + (wv << 3));
    int x0 = wx * 62 - 1;
    int x = x0 + lane;                    // -1 .. 1054
    int xa = x0 & ~7;                     // 16B-aligned stage base col (halves)
    int lx = (x0 - xa) + lane;            // lane's col in stage [0..70]
    bool xok = ((unsigned)x < 1024u);
    float thr = thr_p[0];
    const float NEG = -__builtin_huge_valf();

    // [88 row-pairs][80 cols][2] fp16 = 28160 B
    __shared__ _Float16 stageh[88 * 160];

    int jlo = jlo_t[zc], jhi = jhi_t[zc];
    int istart = jlo > 0 ? jlo - 1 : 0;
    int iend = (jhi + 2 < 50) ? jhi + 2 : 50;

    float gprev[10], A[8], B[8], Dprev[8];
#pragma unroll
    for (int k = 0; k < 10; ++k) gprev[k] = 0.f;
#pragma unroll
    for (int k = 0; k < 8; ++k) { A[k] = NEG; B[k] = NEG; Dprev[k] = 0.f; }

    for (int i = istart; i <= iend; ++i) {
        int r = rarr[i];
        const half2_t* __restrict__ wA = whA + i * WPAIRS + 8;
        const half2_t* __restrict__ wB = whB + i * WPAIRS + 8;
        const _Float16* __restrict__ planeh = tmpHh + ((size_t)i << 20);
        int mcount = ((2 * r + 17) >> 3) << 3;       // >= 2r+10, mult of 8
        int nrp = (mcount + 64) >> 1;                // row-pairs (<= 88)
        int gy0blk = (ybg << 6) - 1 - r;
        __syncthreads();                             // prev conv reads done
        int nch = nrp * 10;                          // chunks: (row-pair, 8 cols)
        for (int e = t; e < nch; e += 512) {
            int rp = e / 10, c = e - rp * 10;
            int gyA = gy0blk + (rp << 1);
            int gyB = gyA + 1;
            int gx = xa + (c << 3);
            half8 va = {(_Float16)0.f, (_Float16)0.f, (_Float16)0.f, (_Float16)0.f,
                        (_Float16)0.f, (_Float16)0.f, (_Float16)0.f, (_Float16)0.f};
            half8 vb = va;
            bool inx = ((unsigned)gx <= 1016u);
            if ((unsigned)gyA < 1024u) {
                const _Float16* rp_ = planeh + ((size_t)gyA << 10);
                if (inx) va = *(const half8*)(rp_ + gx);
                else {
#pragma unroll
                    for (int cc = 0; cc < 8; ++cc) {
                        int g = gx + cc;
                        if ((unsigned)g < 1024u) va[cc] = rp_[g];
                    }
                }
            }
            if ((unsigned)gyB < 1024u) {
                const _Float16* rp_ = planeh + ((size_t)gyB << 10);
                if (inx) vb = *(const half8*)(rp_ + gx);
                else {
#pragma unroll
                    for (int cc = 0; cc < 8; ++cc) {
                        int g = gx + cc;
                        if ((unsigned)g < 1024u) vb[cc] = rp_[g];
                    }
                }
            }
            half8 w0, w1;                            // interleave rows A,B
            w0[0] = va[0]; w0[1] = vb[0]; w0[2] = va[1]; w0[3] = vb[1];
            w0[4] = va[2]; w0[5] = vb[2]; w0[6] = va[3]; w0[7] = vb[3];
            w1[0] = va[4]; w1[1] = vb[4]; w1[2] = va[5]; w1[3] = vb[5];
            w1[4] = va[6]; w1[5] = vb[6]; w1[6] = va[7]; w1[7] = vb[7];
            _Float16* dst = stageh + rp * 160 + (c << 4);
            *(half8*)dst       = w0;
            *(half8*)(dst + 8) = w1;
        }
        __syncthreads();                             // stage visible
        float acc[10];
#pragma unroll
        for (int k = 0; k < 10; ++k) acc[k] = 0.f;
        int b0 = (wv << 2) * 160 + (lx << 1);        // row-pair 4wv, col lx
        for (int m = 0; m < mcount; m += 8) {
            int ib = b0 + (m >> 1) * 160;
            int pb = m >> 1;                         // uniform pair base
            half2_t v[4];
#pragma unroll
            for (int jj = 0; jj < 4; ++jj)
                v[jj] = *(const half2_t*)&stageh[ib + jj * 160];
#pragma unroll
            for (int jj = 0; jj < 4; ++jj)
#pragma unroll
                for (int k = 0; k < 10; ++k) {
                    half2_t wpair = (k & 1) ? wB[pb + jj - ((k + 1) >> 1)]
                                            : wA[pb + jj - (k >> 1)];
                    acc[k] = __builtin_amdgcn_fdot2(v[jj], wpair, acc[k], false);
                }
        }
        // ---- epilogue for scale i ----
        if (i > istart) {
            int d = i - 1;
            float sg = sigmas[d];
#pragma unroll
            for (int k = 0; k < 10; ++k) {           // DoG; -inf outside image
                int gy = y0u - 1 + k;
                bool ok = xok && ((unsigned)gy < 1024u);
                gprev[k] = ok ? (gprev[k] - acc[k]) * sg : NEG;
            }
            float ym[8];
#pragma unroll
            for (int k = 0; k < 8; ++k)
                ym[k] = fmaxf(fmaxf(gprev[k], gprev[k + 1]), gprev[k + 2]);
            if (d - 1 >= jlo) {                      // emit j = d-1
                float pooled[8];
#pragma unroll
                for (int k = 0; k < 8; ++k) {
                    float pn = fmaxf(B[k], ym[k]);
                    float l  = __shfl_up(pn, 1);
                    float rr = __shfl_down(pn, 1);
                    pooled[k] = fmaxf(fmaxf(l, rr), pn);
                }
                if (xok && lane >= 1 && lane <= 62) {
                    int j = d - 1;
#pragma unroll
                    for (int k = 0; k < 8; ++k) {
                        float lm = fmaxf(pooled[k] + thr, 0.f);
                        float sm = 1.f - lm + Dprev[k] + thr;
                        float* orow = out + (((size_t)j << 20)
                                     + ((size_t)(y0u + k) << 10));
                        __builtin_nontemporal_store(lm, orow + x);
                        __builtin_nontemporal_store(sm, orow + DOG_ELEMS + x);
                    }
                }
            }
#pragma unroll
            for (int k = 0; k < 8; ++k) {
                B[k] = fmaxf(A[k], ym[k]);
                A[k] = ym[k];
                Dprev[k] = gprev[k + 1];             // dog center rows
            }
        }
#pragma unroll
        for (int k = 0; k < 10; ++k) gprev[k] = acc[k];
    }
    if (jhi == 49) {                                 // tail: j=49 (ym_50 = -inf)
        float pooled[8];
#pragma unroll
        for (int k = 0; k < 8; ++k) {
            float pn = B[k];
            float l  = __shfl_up(pn, 1);
            float rr = __shfl_down(pn, 1);
            pooled[k] = fmaxf(fmaxf(l, rr), pn);
        }
        if (xok && lane >= 1 && lane <= 62) {
#pragma unroll
            for (int k = 0; k < 8; ++k) {
                float lm = fmaxf(pooled[k] + thr, 0.f);
                float sm = 1.f - lm + Dprev[k] + thr;
                float* orow = out + (((size_t)49 << 20)
                             + ((size_t)(y0u + k) << 10));
                __builtin_nontemporal_store(lm, orow + x);
                __builtin_nontemporal_store(sm, orow + DOG_ELEMS + x);
            }
        }
    }
}

extern "C" void kernel_launch(void* const* d_in, const int* in_sizes, int n_in,
                              void* d_out, int out_size, void* d_ws, size_t ws_size,
                              hipStream_t stream) {
    const float* input  = (const float*)d_in[0];
    const float* weight = (const float*)d_in[1];
    const float* sigmas = (const float*)d_in[2];
    const float* thr    = (const float*)d_in[3];
    float* out = (float*)d_out;

    int S = 103;
    if (n_in > 1 && in_sizes[1] >= NS) {
        int s2 = in_sizes[1] / NS;
        S = (int)(sqrt((double)s2) + 0.5);
    }

    size_t need = (size_t)NS * PLANE * 2 + (size_t)NS * WPSTRIDE * 4
                + 64 * 4 + (size_t)NS * WPAIRS * 4 * 2 + 256;
    if (ws_size < need) return;   // insufficient scratch -> visible validation failure

    _Float16* tmpHh = (_Float16*)d_ws;                       // 51 fp16 planes (107 MB)
    float* wp   = (float*)((char*)d_ws + (size_t)NS * PLANE * 2);
    int*   rarr = (int*)(wp + NS * WPSTRIDE);                // 51 ints (64 slots)
    half2_t* whA = (half2_t*)(rarr + 64);                    // 51*80 pairs
    half2_t* whB = whA + NS * WPAIRS;                        // 51*80 pairs

    dog_prep <<<NS, 128, 0, stream>>>(weight, wp, whA, whB, rarr, S);
    dog_hblur<<<dim3(512, 5), 256, 0, stream>>>(input, tmpHh, wp, rarr);
    dog_fused<<<1408, 512, 0, stream>>>(tmpHh, out, whA, whB, rarr, sigmas, thr);
}